// Round 9
// baseline (157.139 us; speedup 1.0000x reference)
//
#include <hip/hip_runtime.h>

typedef unsigned short u16;
typedef unsigned int u32;

using f32x4  = __attribute__((ext_vector_type(4))) float;
using bf16x8 = __attribute__((ext_vector_type(8))) __bf16;

#define DEV __device__ __forceinline__

DEV u16 f2bf(float f) {                       // RTNE f32 -> bf16
  union { float f; u32 u; } x; x.f = f;
  return (u16)((x.u + 0x7fffu + ((x.u >> 16) & 1u)) >> 16);
}
DEV float bf2f(u16 h) {
  union { u32 u; float f; } x; x.u = ((u32)h) << 16;
  return x.f;
}

DEV void async_cp16(const u16* g, u16* l) {   // 16B global -> LDS direct
  __builtin_amdgcn_global_load_lds((const __attribute__((address_space(1))) void*)g,
                                   (__attribute__((address_space(3))) void*)l,
                                   16, 0, 0);
}

static constexpr int BATCH = 4096;
static constexpr int FEAT  = 512;
static constexpr int EMB   = 64;
static constexpr int HID   = 1024;
static constexpr int NC    = 64;
static constexpr int DIN   = 576;   // FEAT + EMB
static constexpr int LIB   = 256;   // LIB_X == LIB_Y == OUT_J

// ---- cheap per-block dtype / index-width detection (1 load/thread) ---------
DEV void detect_lite(const u32* __restrict__ sraw, const u32* __restrict__ oraw,
                     int* isf32, int* ostr) {
  __shared__ int cib, conz;
  const int t = threadIdx.x;
  if (t == 0) { cib = 0; conz = 0; }
  u32 w = sraw[t];
  u32 e = (w >> 7) & 0xFFu;
  unsigned long long m1 = __ballot(e >= 100 && e <= 142);
  unsigned long long m2 = __ballot((t & 1) && oraw[t] != 0);
  __syncthreads();
  if ((t & 63) == 0) {
    atomicAdd(&cib, __popcll(m1));
    atomicAdd(&conz, __popcll(m2));
  }
  __syncthreads();
  *isf32 = (cib < 128) ? 1 : 0;               // low halves not bf16-like -> f32
  *ostr  = (conz == 0) ? 2 : 1;               // all odd words zero -> int64
}

// ---- load 16 elems at element-offset `off`, convert to bf16 ----------------
DEV void load16_bf(u16* v, const void* __restrict__ in, size_t off, int isf32) {
  if (isf32) {
    const float4* s = (const float4*)((const float*)in + off);
    float4 a0 = s[0], a1 = s[1], a2 = s[2], a3 = s[3];
    v[0] = f2bf(a0.x); v[1] = f2bf(a0.y); v[2]  = f2bf(a0.z); v[3]  = f2bf(a0.w);
    v[4] = f2bf(a1.x); v[5] = f2bf(a1.y); v[6]  = f2bf(a1.z); v[7]  = f2bf(a1.w);
    v[8] = f2bf(a2.x); v[9] = f2bf(a2.y); v[10] = f2bf(a2.z); v[11] = f2bf(a2.w);
    v[12] = f2bf(a3.x); v[13] = f2bf(a3.y); v[14] = f2bf(a3.z); v[15] = f2bf(a3.w);
  } else {
    const uint4* s = (const uint4*)((const u16*)in + off);
    *(uint4*)&v[0] = s[0];
    *(uint4*)&v[8] = s[1];
  }
}

// ---- 64x64 transpose tile (bf16-ifying), vectorized both directions --------
DEV void do_transpose64(u16* lds, const void* __restrict__ in,
                        u16* __restrict__ out, int R, int C,
                        int by, int bx, int isf32) {
  u16* tile = lds;                            // 64*72 u16
  const int t = threadIdx.x;
  {
    const int r = t >> 2, c0 = (t & 3) * 16;
    u16 v[16];
    load16_bf(v, in, (size_t)(by * 64 + r) * C + (bx * 64 + c0), isf32);
    *(uint4*)&tile[r * 72 + c0]     = *(uint4*)&v[0];
    *(uint4*)&tile[r * 72 + c0 + 8] = *(uint4*)&v[8];
  }
  __syncthreads();
  {
    const int c = t & 63, rs = (t >> 6) * 16;
    u16 w[16];
#pragma unroll
    for (int i = 0; i < 16; ++i) w[i] = tile[(rs + i) * 72 + c];
    size_t oo = (size_t)(bx * 64 + c) * R + (by * 64 + rs);
    *(uint4*)&out[oo]     = *(uint4*)&w[0];
    *(uint4*)&out[oo + 8] = *(uint4*)&w[8];
  }
}

// ---- T-gemm: T[j][q] = sum_i nX[i][j] * Wx2[q][i]  (bt layout for gemm2-x) -
DEV void tgemm_task(u16* lds, const void* __restrict__ nX,
                    const void* __restrict__ Wx2, u16* __restrict__ T,
                    int mt, int nt, int isf32) {
  u16* Als = lds;                 // [64 j][72]  (64 i-slab + pad)
  u16* Bls = lds + 64 * 72;       // [2*64 q][32]
  const int t = threadIdx.x;
  const int m0 = mt * 64, q0 = nt * 64;
  const int lane = t & 63, wid = t >> 6;
  const int wm = wid >> 1, wn = wid & 1;
  const int lr = lane & 15, lq = lane >> 4;
  f32x4 acc[2][2] = {};
  for (int k0 = 0; k0 < LIB; k0 += 64) {
    __syncthreads();
    {
      const int r = t >> 2, c0 = (t & 3) * 16;
      u16 v[16];
      load16_bf(v, nX, (size_t)(k0 + r) * LIB + m0 + c0, isf32);
#pragma unroll
      for (int j = 0; j < 16; ++j) Als[(c0 + j) * 72 + r] = v[j];
      const int q = t >> 2, ic = (t & 3) * 16;
      u16 w16[16];
      load16_bf(w16, Wx2, (size_t)(q0 + q) * LIB + k0 + ic, isf32);
      u16* dst = &Bls[((ic >> 5) * 64 + q) * 32 + (ic & 31)];
      *(uint4*)dst       = *(uint4*)&w16[0];
      *(uint4*)(dst + 8) = *(uint4*)&w16[8];
    }
    __syncthreads();
#pragma unroll
    for (int sl = 0; sl < 2; ++sl) {
      bf16x8 av[2], bv[2];
#pragma unroll
      for (int i2 = 0; i2 < 2; ++i2)
        av[i2] = *(const bf16x8*)&Als[(wm * 32 + i2 * 16 + lr) * 72 + sl * 32 + lq * 8];
#pragma unroll
      for (int j2 = 0; j2 < 2; ++j2)
        bv[j2] = *(const bf16x8*)&Bls[(sl * 64 + wn * 32 + j2 * 16 + lr) * 32 + lq * 8];
#pragma unroll
      for (int i2 = 0; i2 < 2; ++i2)
#pragma unroll
        for (int j2 = 0; j2 < 2; ++j2)
          acc[i2][j2] = __builtin_amdgcn_mfma_f32_16x16x32_bf16(av[i2], bv[j2], acc[i2][j2], 0, 0, 0);
    }
  }
#pragma unroll
  for (int j2 = 0; j2 < 2; ++j2) {
    const int gc = q0 + wn * 32 + j2 * 16 + lr;
#pragma unroll
    for (int i2 = 0; i2 < 2; ++i2) {
      const int gr = m0 + wm * 32 + i2 * 16 + lq * 4;
#pragma unroll
      for (int r = 0; r < 4; ++r)
        T[(size_t)(gr + r) * HID + gc] = f2bf(acc[i2][j2][r]);
    }
  }
}

// ---- prep: concat | WT1x | WT1y | WT2y  (pure copies, 9.2 KB LDS) ----------
struct PrepArgs {
  const void *state, *emb, *Wx1, *Wy1, *Wy2;
  const int* opt;
  u16 *all_state, *WT1x, *WT1y, *WT2y;
};
static constexpr int PB_CONCAT = BATCH * 36 / 256;            // 576
static constexpr int PB_WT1 = (DIN / 64) * (HID / 64);        // 144
static constexpr int PB_WT2 = (HID / 64) * (LIB / 64);        // 64
static constexpr int PREP_BLOCKS = PB_CONCAT + 2 * PB_WT1 + PB_WT2;  // 928

__global__ __launch_bounds__(256) void prep_k(PrepArgs a) {
  __shared__ __align__(16) u16 plds[64 * 72];                 // 9216 B
  int isf32, os;
  detect_lite((const u32*)a.state, (const u32*)a.opt, &isf32, &os);
  int bid = blockIdx.x;
  const int t = threadIdx.x;
  if (bid < PB_CONCAT) {
    int idx = bid * 256 + t;
    int b = idx / 36, ch = idx % 36;
    const void* base;
    size_t srcoff;
    if (ch < 32) { base = a.state; srcoff = (size_t)b * FEAT + ch * 16; }
    else {
      base = a.emb;
      srcoff = (size_t)a.opt[(size_t)b * os] * EMB + (ch - 32) * 16;
    }
    u16 o[16];
    load16_bf(o, base, srcoff, isf32);
    u16* dst = a.all_state + (size_t)b * DIN + ch * 16;
    *(uint4*)dst       = *(const uint4*)&o[0];
    *(uint4*)(dst + 8) = *(const uint4*)&o[8];
    return;
  }
  bid -= PB_CONCAT;
  if (bid < PB_WT1) { do_transpose64(plds, a.Wx1, a.WT1x, DIN, HID, bid >> 4, bid & 15, isf32); return; }
  bid -= PB_WT1;
  if (bid < PB_WT1) { do_transpose64(plds, a.Wy1, a.WT1y, DIN, HID, bid >> 4, bid & 15, isf32); return; }
  bid -= PB_WT1;
  do_transpose64(plds, a.Wy2, a.WT2y, HID, LIB, bid >> 2, bid & 3, isf32);
}

// ---- bt-GEMM tile, BK=64 dual-slab: C = act(A[M,K]*Bt[N,K]^T + bias) -------
template <int BM, int BN, bool RELU>
DEV void gemm_tile(u16* lds, const u16* __restrict__ A, const u16* __restrict__ Bt,
                   const void* bias, void* C, int N, int K, int m0, int n0,
                   int isf32, bool cf32, bool bf32) {
  constexpr int WM = BM / 2, WN = BN / 2, TM = WM / 16, TN = WN / 16;
  u16* As = lds;                  // [2][BM][32]
  u16* Bs = lds + BM * 64;        // [2][BN][32]
  const int t = threadIdx.x;
  const int lane = t & 63, wid = t >> 6;
  const int wm = wid >> 1, wn = wid & 1;
  const int lr = lane & 15, lq = lane >> 4;
  f32x4 acc[TM][TN] = {};
  for (int k0 = 0; k0 < K; k0 += 64) {
    __syncthreads();
#pragma unroll
    for (int sl = 0; sl < 2; ++sl) {
#pragma unroll
      for (int u = 0; u < BM / 64; ++u) {
        int unit = u * 256 + t;
        int r = unit >> 2, c8 = (unit & 3) * 8;
        async_cp16(A + (size_t)(m0 + r) * K + (k0 + sl * 32 + c8),
                   &As[(sl * BM + r) * 32 + c8]);
      }
#pragma unroll
      for (int u = 0; u < BN / 64; ++u) {
        int unit = u * 256 + t;
        int r = unit >> 2, c8 = (unit & 3) * 8;
        async_cp16(Bt + (size_t)(n0 + r) * K + (k0 + sl * 32 + c8),
                   &Bs[(sl * BN + r) * 32 + c8]);
      }
    }
    __syncthreads();
#pragma unroll
    for (int sl = 0; sl < 2; ++sl) {
      bf16x8 av[TM], bv[TN];
#pragma unroll
      for (int i = 0; i < TM; ++i)
        av[i] = *(const bf16x8*)&As[(sl * BM + wm * WM + i * 16 + lr) * 32 + lq * 8];
#pragma unroll
      for (int j = 0; j < TN; ++j)
        bv[j] = *(const bf16x8*)&Bs[(sl * BN + wn * WN + j * 16 + lr) * 32 + lq * 8];
#pragma unroll
      for (int i = 0; i < TM; ++i)
#pragma unroll
        for (int j = 0; j < TN; ++j)
          acc[i][j] = __builtin_amdgcn_mfma_f32_16x16x32_bf16(av[i], bv[j], acc[i][j], 0, 0, 0);
    }
  }
  // epilogue: C/D layout col=lane&15, row=(lane>>4)*4+r  [m89/m91 verified]
#pragma unroll
  for (int j = 0; j < TN; ++j) {
    const int gc = n0 + wn * WN + j * 16 + lr;
    const float bval = bias
        ? (bf32 ? ((const float*)bias)[gc] : bf2f(((const u16*)bias)[gc]))
        : 0.f;
#pragma unroll
    for (int i = 0; i < TM; ++i) {
      const int gr = m0 + wm * WM + i * 16 + lq * 4;
#pragma unroll
      for (int r = 0; r < 4; ++r) {
        float v = acc[i][j][r] + bval;
        if (RELU) v = fmaxf(v, 0.f);
        const size_t idx = (size_t)(gr + r) * N + gc;
        if (cf32) ((float*)C)[idx] = v;
        else      ((u16*)C)[idx] = f2bf(v);
      }
    }
  }
}

// ---- gemm1: layer-1 both heads, XCD-swizzled 1D grid + TG/bias side-tasks --
// bid<512: gemm block. XCD = bid%8 -> fixed (head, n_lo) pair; n_hi = bit3;
// m = bid>>4. Each XCD holds 2 B n-tiles in L2 and streams A exactly once.
struct G1Args {
  const u16 *all_state, *WT1x, *WT1y;
  const void *bx1, *by1, *nX, *Wx2, *bx2, *state, *opt;
  u16 *h_x, *h_y, *T;
  float* b2x;
};

__global__ __launch_bounds__(256) void gemm1_k(G1Args a) {
  __shared__ __align__(16) u16 lds[256 * 64];   // 32 KB (gemm) / 17.4 KB (TG)
  __shared__ float red[4][64];
  int isf32, os;
  detect_lite((const u32*)a.state, (const u32*)a.opt, &isf32, &os);
  const int g = blockIdx.x, t = threadIdx.x;
  if (g < 512) {
    const int c = g & 7;
    const int head = c & 1;
    const int n = (c >> 1) | (((g >> 3) & 1) << 2);
    const int m = g >> 4;
    gemm_tile<128, 128, true>(lds,
        a.all_state, head ? a.WT1y : a.WT1x, head ? a.by1 : a.bx1,
        head ? a.h_y : a.h_x, HID, DIN, m * 128, n * 128, isf32, false, isf32);
    return;
  }
  if (g < 576) {
    const int id = g - 512;
    tgemm_task(lds, a.nX, a.Wx2, a.T, id & 3, id >> 2, isf32);
    return;
  }
  // bias': b2x[j] = sum_i bx2[i] * nX[i][j]  (4 blocks x 64 j, i-parallel x4)
  {
    const int bid = g - 576;
    const int j = bid * 64 + (t & 63), grp = t >> 6;
    float acc = 0.f;
    for (int ii = 0; ii < 64; ++ii) {
      const int i = grp * 64 + ii;
      float s = isf32 ? ((const float*)a.bx2)[i] : bf2f(((const u16*)a.bx2)[i]);
      float v = isf32 ? ((const float*)a.nX)[(size_t)i * LIB + j]
                      : bf2f(((const u16*)a.nX)[(size_t)i * LIB + j]);
      acc += s * v;
    }
    red[grp][t & 63] = acc;
    __syncthreads();
    if (grp == 0)
      a.b2x[j] = red[0][t & 63] + red[1][t & 63] + red[2][t & 63] + red[3][t & 63];
  }
}

struct GArg { const u16* A; const u16* Bt; const void* bias; void* C; int cflag; int bflag; };

// r6-proven orientation: x = n-tile, y = m-tile, z = head
template <int BM, int BN, bool RELU>
__global__ __launch_bounds__(256) void gemm_bt(GArg g0, GArg g1, int N, int K,
                                               const void* state, const void* opt) {
  __shared__ __align__(16) u16 lds[(BM + BN) * 64];
  int isf32, os;
  detect_lite((const u32*)state, (const u32*)opt, &isf32, &os);
  const GArg g = blockIdx.z ? g1 : g0;
  gemm_tile<BM, BN, RELU>(lds, g.A, g.Bt, g.bias, g.C, N, K,
                          blockIdx.y * BM, blockIdx.x * BN,
                          isf32, g.cflag && isf32, g.bflag || isf32);
}

// ---- tail: routed gatherY only (m = bid>>2, 4 col-tiles per class) ---------
struct TailArgs {
  const u16* cls_y;
  const void *nY, *state;
  const int* opt;
  void* out;            // out1 at BATCH*LIB
};

__global__ __launch_bounds__(256) void tail_k(TailArgs a) {
  __shared__ __align__(16) u16 lds[25216];  // Bts 64x264 | Asm 16x264 | list 4096
  __shared__ int wcnt[4], lbase;
  int isf32, os;
  detect_lite((const u32*)a.state, (const u32*)a.opt, &isf32, &os);
  const bool of32 = (isf32 != 0);
  const int t = threadIdx.x;
  const int lane = t & 63, w = t >> 6, lr = lane & 15, lq = lane >> 4;

  u16* Bts  = lds;            // [64 n][264]  B[n][k] = nY[m][k][n0+n]
  u16* Asm  = lds + 16896;    // [16][264]
  u16* list = lds + 21120;    // up to 4096 row ids
  const int m = blockIdx.x >> 2, n0 = (blockIdx.x & 3) * 64;

#pragma unroll
  for (int pass = 0; pass < 4; ++pass) {
    const int k = pass * 64 + (t >> 2), nc = (t & 3) * 16;
    u16 v[16];
    load16_bf(v, a.nY, ((size_t)m * LIB + k) * LIB + n0 + nc, isf32);
#pragma unroll
    for (int j = 0; j < 16; ++j) Bts[(nc + j) * 264 + k] = v[j];
  }

  // build row list for class m: ballot + wave-prefix compaction (b-ordered)
  if (t == 0) lbase = 0;
  __syncthreads();
  for (int base = 0; base < BATCH; base += 256) {
    const int b = base + t;
    const int e = a.opt[(size_t)b * os];
    unsigned long long mk = __ballot(e == m);
    if (lane == 0) wcnt[w] = __popcll(mk);
    __syncthreads();
    int wpre = lbase;
    for (int i = 0; i < w; ++i) wpre += wcnt[i];
    const int mypre = __popcll(mk & ((1ull << lane) - 1ull));
    if (e == m) list[wpre + mypre] = (u16)b;
    __syncthreads();
    if (t == 0) lbase += wcnt[0] + wcnt[1] + wcnt[2] + wcnt[3];
  }
  __syncthreads();
  const int cnt = lbase;
  const size_t out_off = (size_t)BATCH * LIB;

  for (int ch = 0; ch < cnt; ch += 16) {
    __syncthreads();
    {
      const int r = t >> 4, cb = (t & 15) * 16;
      if (ch + r < cnt) {
        const u16* src = a.cls_y + (size_t)list[ch + r] * LIB + cb;
        *(uint4*)&Asm[r * 264 + cb]     = *(const uint4*)src;
        *(uint4*)&Asm[r * 264 + cb + 8] = *(const uint4*)(src + 8);
      } else {
        uint4 z{0, 0, 0, 0};
        *(uint4*)&Asm[r * 264 + cb]     = z;
        *(uint4*)&Asm[r * 264 + cb + 8] = z;
      }
    }
    __syncthreads();
    f32x4 acc = {};
#pragma unroll
    for (int kk = 0; kk < LIB; kk += 32) {
      bf16x8 av = *(const bf16x8*)&Asm[lr * 264 + kk + lq * 8];
      bf16x8 bv = *(const bf16x8*)&Bts[(w * 16 + lr) * 264 + kk + lq * 8];
      acc = __builtin_amdgcn_mfma_f32_16x16x32_bf16(av, bv, acc, 0, 0, 0);
    }
#pragma unroll
    for (int r = 0; r < 4; ++r) {
      const int rowc = lq * 4 + r;
      if (ch + rowc < cnt) {
        const size_t oi = out_off + (size_t)list[ch + rowc] * LIB
                        + (n0 + w * 16 + lr);
        if (of32) ((float*)a.out)[oi] = acc[r];
        else      ((u16*)a.out)[oi] = f2bf(acc[r]);
      }
    }
  }
}

extern "C" void kernel_launch(void* const* d_in, const int* in_sizes, int n_in,
                              void* d_out, int out_size, void* d_ws, size_t ws_size,
                              hipStream_t stream) {
  char* p = (char*)d_ws;
  auto alloc = [&](size_t bytes) { char* r = p; p += (bytes + 255) & ~(size_t)255; return r; };
  u16* all_state = (u16*)alloc((size_t)BATCH * DIN * 2);
  u16* h_x   = (u16*)alloc((size_t)BATCH * HID * 2);
  u16* h_y   = (u16*)alloc((size_t)BATCH * HID * 2);
  u16* cls_y = (u16*)alloc((size_t)BATCH * LIB * 2);
  u16* WT1x  = (u16*)alloc((size_t)HID * DIN * 2);
  u16* WT1y  = (u16*)alloc((size_t)HID * DIN * 2);
  u16* WT2y  = (u16*)alloc((size_t)LIB * HID * 2);
  u16* T     = (u16*)alloc((size_t)LIB * HID * 2);   // (Wx2@nX)^T, bt layout
  float* b2x = (float*)alloc((size_t)LIB * 4);       // nX^T @ bx2, f32

  const void* state = d_in[0];
  const void* opt   = d_in[1];

  // 1) prep: concat + WT1x/WT1y/WT2y (928 pure-copy blocks, 9.2 KB LDS)
  PrepArgs pa;
  pa.state = state; pa.opt = (const int*)opt; pa.emb = d_in[2];
  pa.Wx1 = d_in[3]; pa.Wy1 = d_in[7]; pa.Wy2 = d_in[9];
  pa.all_state = all_state; pa.WT1x = WT1x; pa.WT1y = WT1y; pa.WT2y = WT2y;
  prep_k<<<PREP_BLOCKS, 256, 0, stream>>>(pa);

  // 2) layer 1 (relu) both heads, XCD-swizzled + TG/bias side-tasks (580 blk)
  G1Args g1;
  g1.all_state = all_state; g1.WT1x = WT1x; g1.WT1y = WT1y;
  g1.bx1 = d_in[4]; g1.by1 = d_in[8];
  g1.nX = d_in[11]; g1.Wx2 = d_in[5]; g1.bx2 = d_in[6];
  g1.state = state; g1.opt = opt;
  g1.h_x = h_x; g1.h_y = h_y; g1.T = T; g1.b2x = b2x;
  gemm1_k<<<580, 256, 0, stream>>>(g1);

  // 3) fused layer-2: z=0 -> out0 = h_x @ T^T + b' (direct, dtype per flag)
  //                   z=1 -> cls_y = h_y @ Wy2^T + by2 (bf16 internal)
  GArg g2x{h_x, T, b2x, d_out, 1, 1};
  GArg g2y{h_y, WT2y, d_in[10], cls_y, 0, 0};
  gemm_bt<64, 64, false><<<dim3(LIB / 64, BATCH / 64, 2), 256, 0, stream>>>(
      g2x, g2y, LIB, HID, state, opt);

  // 4) tail: routed gatherY only -> out1 (256 blocks)
  TailArgs ta{cls_y, d_in[12], state, (const int*)opt, d_out};
  tail_k<<<256, 256, 0, stream>>>(ta);
}

// Round 10
// 152.360 us; speedup vs baseline: 1.0314x; 1.0314x over previous
//
#include <hip/hip_runtime.h>

typedef unsigned short u16;
typedef unsigned int u32;

using f32x4  = __attribute__((ext_vector_type(4))) float;
using bf16x8 = __attribute__((ext_vector_type(8))) __bf16;

#define DEV __device__ __forceinline__

DEV u16 f2bf(float f) {                       // RTNE f32 -> bf16
  union { float f; u32 u; } x; x.f = f;
  return (u16)((x.u + 0x7fffu + ((x.u >> 16) & 1u)) >> 16);
}
DEV float bf2f(u16 h) {
  union { u32 u; float f; } x; x.u = ((u32)h) << 16;
  return x.f;
}

DEV void async_cp16(const u16* g, u16* l) {   // 16B global -> LDS direct
  __builtin_amdgcn_global_load_lds((const __attribute__((address_space(1))) void*)g,
                                   (__attribute__((address_space(3))) void*)l,
                                   16, 0, 0);
}

static constexpr int BATCH = 4096;
static constexpr int FEAT  = 512;
static constexpr int EMB   = 64;
static constexpr int HID   = 1024;
static constexpr int NC    = 64;
static constexpr int DIN   = 576;   // FEAT + EMB
static constexpr int LIB   = 256;   // LIB_X == LIB_Y == OUT_J

// ---- cheap per-block dtype / index-width detection (1 load/thread) ---------
DEV void detect_lite(const u32* __restrict__ sraw, const u32* __restrict__ oraw,
                     int* isf32, int* ostr) {
  __shared__ int cib, conz;
  const int t = threadIdx.x;
  if (t == 0) { cib = 0; conz = 0; }
  u32 w = sraw[t];
  u32 e = (w >> 7) & 0xFFu;
  unsigned long long m1 = __ballot(e >= 100 && e <= 142);
  unsigned long long m2 = __ballot((t & 1) && oraw[t] != 0);
  __syncthreads();
  if ((t & 63) == 0) {
    atomicAdd(&cib, __popcll(m1));
    atomicAdd(&conz, __popcll(m2));
  }
  __syncthreads();
  *isf32 = (cib < 128) ? 1 : 0;               // low halves not bf16-like -> f32
  *ostr  = (conz == 0) ? 2 : 1;               // all odd words zero -> int64
}

// ---- load 16 elems at element-offset `off`, convert to bf16 ----------------
DEV void load16_bf(u16* v, const void* __restrict__ in, size_t off, int isf32) {
  if (isf32) {
    const float4* s = (const float4*)((const float*)in + off);
    float4 a0 = s[0], a1 = s[1], a2 = s[2], a3 = s[3];
    v[0] = f2bf(a0.x); v[1] = f2bf(a0.y); v[2]  = f2bf(a0.z); v[3]  = f2bf(a0.w);
    v[4] = f2bf(a1.x); v[5] = f2bf(a1.y); v[6]  = f2bf(a1.z); v[7]  = f2bf(a1.w);
    v[8] = f2bf(a2.x); v[9] = f2bf(a2.y); v[10] = f2bf(a2.z); v[11] = f2bf(a2.w);
    v[12] = f2bf(a3.x); v[13] = f2bf(a3.y); v[14] = f2bf(a3.z); v[15] = f2bf(a3.w);
  } else {
    const uint4* s = (const uint4*)((const u16*)in + off);
    *(uint4*)&v[0] = s[0];
    *(uint4*)&v[8] = s[1];
  }
}

// ---- 64x64 transpose tile (bf16-ifying), vectorized both directions --------
DEV void do_transpose64(u16* lds, const void* __restrict__ in,
                        u16* __restrict__ out, int R, int C,
                        int by, int bx, int isf32) {
  u16* tile = lds;                            // 64*72 u16
  const int t = threadIdx.x;
  {
    const int r = t >> 2, c0 = (t & 3) * 16;
    u16 v[16];
    load16_bf(v, in, (size_t)(by * 64 + r) * C + (bx * 64 + c0), isf32);
    *(uint4*)&tile[r * 72 + c0]     = *(uint4*)&v[0];
    *(uint4*)&tile[r * 72 + c0 + 8] = *(uint4*)&v[8];
  }
  __syncthreads();
  {
    const int c = t & 63, rs = (t >> 6) * 16;
    u16 w[16];
#pragma unroll
    for (int i = 0; i < 16; ++i) w[i] = tile[(rs + i) * 72 + c];
    size_t oo = (size_t)(bx * 64 + c) * R + (by * 64 + rs);
    *(uint4*)&out[oo]     = *(uint4*)&w[0];
    *(uint4*)&out[oo + 8] = *(uint4*)&w[8];
  }
}

// ---- T-gemm: T[j][q] = sum_i nX[i][j] * Wx2[q][i]  (bt layout for gemm2-x) -
DEV void tgemm_task(u16* lds, const void* __restrict__ nX,
                    const void* __restrict__ Wx2, u16* __restrict__ T,
                    int mt, int nt, int isf32) {
  u16* Als = lds;                 // [64 j][72]  (64 i-slab + pad)
  u16* Bls = lds + 64 * 72;       // [2*64 q][32]
  const int t = threadIdx.x;
  const int m0 = mt * 64, q0 = nt * 64;
  const int lane = t & 63, wid = t >> 6;
  const int wm = wid >> 1, wn = wid & 1;
  const int lr = lane & 15, lq = lane >> 4;
  f32x4 acc[2][2] = {};
  for (int k0 = 0; k0 < LIB; k0 += 64) {
    __syncthreads();
    {
      const int r = t >> 2, c0 = (t & 3) * 16;
      u16 v[16];
      load16_bf(v, nX, (size_t)(k0 + r) * LIB + m0 + c0, isf32);
#pragma unroll
      for (int j = 0; j < 16; ++j) Als[(c0 + j) * 72 + r] = v[j];
      const int q = t >> 2, ic = (t & 3) * 16;
      u16 w16[16];
      load16_bf(w16, Wx2, (size_t)(q0 + q) * LIB + k0 + ic, isf32);
      u16* dst = &Bls[((ic >> 5) * 64 + q) * 32 + (ic & 31)];
      *(uint4*)dst       = *(uint4*)&w16[0];
      *(uint4*)(dst + 8) = *(uint4*)&w16[8];
    }
    __syncthreads();
#pragma unroll
    for (int sl = 0; sl < 2; ++sl) {
      bf16x8 av[2], bv[2];
#pragma unroll
      for (int i2 = 0; i2 < 2; ++i2)
        av[i2] = *(const bf16x8*)&Als[(wm * 32 + i2 * 16 + lr) * 72 + sl * 32 + lq * 8];
#pragma unroll
      for (int j2 = 0; j2 < 2; ++j2)
        bv[j2] = *(const bf16x8*)&Bls[(sl * 64 + wn * 32 + j2 * 16 + lr) * 32 + lq * 8];
#pragma unroll
      for (int i2 = 0; i2 < 2; ++i2)
#pragma unroll
        for (int j2 = 0; j2 < 2; ++j2)
          acc[i2][j2] = __builtin_amdgcn_mfma_f32_16x16x32_bf16(av[i2], bv[j2], acc[i2][j2], 0, 0, 0);
    }
  }
#pragma unroll
  for (int j2 = 0; j2 < 2; ++j2) {
    const int gc = q0 + wn * 32 + j2 * 16 + lr;
#pragma unroll
    for (int i2 = 0; i2 < 2; ++i2) {
      const int gr = m0 + wm * 32 + i2 * 16 + lq * 4;
#pragma unroll
      for (int r = 0; r < 4; ++r)
        T[(size_t)(gr + r) * HID + gc] = f2bf(acc[i2][j2][r]);
    }
  }
}

// ---- prep: concat | WT1x | WT1y | WT2y | T-gemm | bias' (r8-proven) --------
struct PrepArgs {
  const void *state, *emb, *Wx1, *Wy1, *Wy2, *Wx2, *nX, *bx2;
  const int* opt;
  u16 *all_state, *WT1x, *WT1y, *WT2y, *T;
  float* b2x;
};
static constexpr int PB_CONCAT = BATCH * 36 / 256;            // 576
static constexpr int PB_WT1 = (DIN / 64) * (HID / 64);        // 144
static constexpr int PB_WT2 = (HID / 64) * (LIB / 64);        // 64
static constexpr int PB_TG  = (LIB / 64) * (HID / 64);        // 64
static constexpr int PB_BIAS = 4;
static constexpr int PREP_BLOCKS = PB_CONCAT + 2 * PB_WT1 + PB_WT2 + PB_TG
                                 + PB_BIAS;                   // 996

__global__ __launch_bounds__(256) void prep_k(PrepArgs a) {
  __shared__ __align__(16) u16 plds[64 * 72 + 128 * 32];      // 17408 B
  __shared__ float red[4][64];
  int isf32, os;
  detect_lite((const u32*)a.state, (const u32*)a.opt, &isf32, &os);
  int bid = blockIdx.x;
  const int t = threadIdx.x;
  if (bid < PB_CONCAT) {
    int idx = bid * 256 + t;
    int b = idx / 36, ch = idx % 36;
    const void* base;
    size_t srcoff;
    if (ch < 32) { base = a.state; srcoff = (size_t)b * FEAT + ch * 16; }
    else {
      base = a.emb;
      srcoff = (size_t)a.opt[(size_t)b * os] * EMB + (ch - 32) * 16;
    }
    u16 o[16];
    load16_bf(o, base, srcoff, isf32);
    u16* dst = a.all_state + (size_t)b * DIN + ch * 16;
    *(uint4*)dst       = *(const uint4*)&o[0];
    *(uint4*)(dst + 8) = *(const uint4*)&o[8];
    return;
  }
  bid -= PB_CONCAT;
  if (bid < PB_WT1) { do_transpose64(plds, a.Wx1, a.WT1x, DIN, HID, bid >> 4, bid & 15, isf32); return; }
  bid -= PB_WT1;
  if (bid < PB_WT1) { do_transpose64(plds, a.Wy1, a.WT1y, DIN, HID, bid >> 4, bid & 15, isf32); return; }
  bid -= PB_WT1;
  if (bid < PB_WT2) { do_transpose64(plds, a.Wy2, a.WT2y, HID, LIB, bid >> 2, bid & 3, isf32); return; }
  bid -= PB_WT2;
  if (bid < PB_TG) { tgemm_task(plds, a.nX, a.Wx2, a.T, bid & 3, bid >> 2, isf32); return; }
  bid -= PB_TG;
  // bias': b2x[j] = sum_i bx2[i] * nX[i][j]  (4 blocks x 64 j, i-parallel x4)
  {
    const int j = bid * 64 + (t & 63), g = t >> 6;
    float acc = 0.f;
    for (int ii = 0; ii < 64; ++ii) {
      const int i = g * 64 + ii;
      float s = isf32 ? ((const float*)a.bx2)[i] : bf2f(((const u16*)a.bx2)[i]);
      float v = isf32 ? ((const float*)a.nX)[(size_t)i * LIB + j]
                      : bf2f(((const u16*)a.nX)[(size_t)i * LIB + j]);
      acc += s * v;
    }
    red[g][t & 63] = acc;
    __syncthreads();
    if (g == 0)
      a.b2x[j] = red[0][t & 63] + red[1][t & 63] + red[2][t & 63] + red[3][t & 63];
  }
}

// ---- bt-GEMM tile, BK=32*SLABS multi-slab: C = act(A*Bt^T + bias) ----------
template <int BM, int BN, int SLABS, bool RELU>
DEV void gemm_tile(u16* lds, const u16* __restrict__ A, const u16* __restrict__ Bt,
                   const void* bias, void* C, int N, int K, int m0, int n0,
                   int isf32, bool cf32, bool bf32) {
  constexpr int WM = BM / 2, WN = BN / 2, TM = WM / 16, TN = WN / 16;
  u16* As = lds;                       // [SLABS][BM][32]
  u16* Bs = lds + BM * 32 * SLABS;     // [SLABS][BN][32]
  const int t = threadIdx.x;
  const int lane = t & 63, wid = t >> 6;
  const int wm = wid >> 1, wn = wid & 1;
  const int lr = lane & 15, lq = lane >> 4;
  f32x4 acc[TM][TN] = {};
  for (int k0 = 0; k0 < K; k0 += 32 * SLABS) {
    __syncthreads();
#pragma unroll
    for (int sl = 0; sl < SLABS; ++sl) {
#pragma unroll
      for (int u = 0; u < BM / 64; ++u) {
        int unit = u * 256 + t;
        int r = unit >> 2, c8 = (unit & 3) * 8;
        async_cp16(A + (size_t)(m0 + r) * K + (k0 + sl * 32 + c8),
                   &As[(sl * BM + r) * 32 + c8]);
      }
#pragma unroll
      for (int u = 0; u < BN / 64; ++u) {
        int unit = u * 256 + t;
        int r = unit >> 2, c8 = (unit & 3) * 8;
        async_cp16(Bt + (size_t)(n0 + r) * K + (k0 + sl * 32 + c8),
                   &Bs[(sl * BN + r) * 32 + c8]);
      }
    }
    __syncthreads();
#pragma unroll
    for (int sl = 0; sl < SLABS; ++sl) {
      bf16x8 av[TM], bv[TN];
#pragma unroll
      for (int i = 0; i < TM; ++i)
        av[i] = *(const bf16x8*)&As[(sl * BM + wm * WM + i * 16 + lr) * 32 + lq * 8];
#pragma unroll
      for (int j = 0; j < TN; ++j)
        bv[j] = *(const bf16x8*)&Bs[(sl * BN + wn * WN + j * 16 + lr) * 32 + lq * 8];
#pragma unroll
      for (int i = 0; i < TM; ++i)
#pragma unroll
        for (int j = 0; j < TN; ++j)
          acc[i][j] = __builtin_amdgcn_mfma_f32_16x16x32_bf16(av[i], bv[j], acc[i][j], 0, 0, 0);
    }
  }
  // epilogue: C/D layout col=lane&15, row=(lane>>4)*4+r  [m89/m91 verified]
#pragma unroll
  for (int j = 0; j < TN; ++j) {
    const int gc = n0 + wn * WN + j * 16 + lr;
    const float bval = bias
        ? (bf32 ? ((const float*)bias)[gc] : bf2f(((const u16*)bias)[gc]))
        : 0.f;
#pragma unroll
    for (int i = 0; i < TM; ++i) {
      const int gr = m0 + wm * WM + i * 16 + lq * 4;
#pragma unroll
      for (int r = 0; r < 4; ++r) {
        float v = acc[i][j][r] + bval;
        if (RELU) v = fmaxf(v, 0.f);
        const size_t idx = (size_t)(gr + r) * N + gc;
        if (cf32) ((float*)C)[idx] = v;
        else      ((u16*)C)[idx] = f2bf(v);
      }
    }
  }
}

struct GArg { const u16* A; const u16* Bt; const void* bias; void* C; int cflag; int bflag; };

// r6-proven orientation: x = n-tile, y = m-tile, z = head
template <int BM, int BN, int SLABS, bool RELU>
__global__ __launch_bounds__(256) void gemm_bt(GArg g0, GArg g1, int N, int K,
                                               const void* state, const void* opt) {
  __shared__ __align__(16) u16 lds[(BM + BN) * 32 * SLABS];
  int isf32, os;
  detect_lite((const u32*)state, (const u32*)opt, &isf32, &os);
  const GArg g = blockIdx.z ? g1 : g0;
  gemm_tile<BM, BN, SLABS, RELU>(lds, g.A, g.Bt, g.bias, g.C, N, K,
                                 blockIdx.y * BM, blockIdx.x * BN,
                                 isf32, g.cflag && isf32, g.bflag || isf32);
}

// ---- tail: routed gatherY only (m = bid>>2, 4 col-tiles per class) ---------
struct TailArgs {
  const u16* cls_y;
  const void *nY, *state;
  const int* opt;
  void* out;            // out1 at BATCH*LIB
};

__global__ __launch_bounds__(256) void tail_k(TailArgs a) {
  __shared__ __align__(16) u16 lds[25216];  // Bts 64x264 | Asm 16x264 | list 4096
  __shared__ int lcnt;
  int isf32, os;
  detect_lite((const u32*)a.state, (const u32*)a.opt, &isf32, &os);
  const bool of32 = (isf32 != 0);
  const int t = threadIdx.x;
  const int lane = t & 63, w = t >> 6, lr = lane & 15, lq = lane >> 4;

  u16* Bts  = lds;            // [64 n][264]  B[n][k] = nY[m][k][n0+n]
  u16* Asm  = lds + 16896;    // [16][264]
  u16* list = lds + 21120;    // up to 4096 row ids
  const int m = blockIdx.x >> 2, n0 = (blockIdx.x & 3) * 64;
  if (t == 0) lcnt = 0;

#pragma unroll
  for (int pass = 0; pass < 4; ++pass) {
    const int k = pass * 64 + (t >> 2), nc = (t & 3) * 16;
    u16 v[16];
    load16_bf(v, a.nY, ((size_t)m * LIB + k) * LIB + n0 + nc, isf32);
#pragma unroll
    for (int j = 0; j < 16; ++j) Bts[(nc + j) * 264 + k] = v[j];
  }

  // build row list for class m: per-wave chunk reservation, no barriers in
  // the scan loop (list order is irrelevant -- each row's output independent)
  __syncthreads();            // lcnt=0 visible
  for (int base = 0; base < BATCH; base += 256) {
    const int b = base + t;
    const int e = a.opt[(size_t)b * os];
    unsigned long long mk = __ballot(e == m);
    const int nw = __popcll(mk);
    int wbase = 0;
    if (lane == 0 && nw) wbase = atomicAdd(&lcnt, nw);
    wbase = __shfl(wbase, 0);
    const int mypre = __popcll(mk & ((1ull << lane) - 1ull));
    if (e == m) list[wbase + mypre] = (u16)b;
  }
  __syncthreads();
  const int cnt = lcnt;
  const size_t out_off = (size_t)BATCH * LIB;

  for (int ch = 0; ch < cnt; ch += 16) {
    __syncthreads();
    {
      const int r = t >> 4, cb = (t & 15) * 16;
      if (ch + r < cnt) {
        const u16* src = a.cls_y + (size_t)list[ch + r] * LIB + cb;
        *(uint4*)&Asm[r * 264 + cb]     = *(const uint4*)src;
        *(uint4*)&Asm[r * 264 + cb + 8] = *(const uint4*)(src + 8);
      } else {
        uint4 z{0, 0, 0, 0};
        *(uint4*)&Asm[r * 264 + cb]     = z;
        *(uint4*)&Asm[r * 264 + cb + 8] = z;
      }
    }
    __syncthreads();
    f32x4 acc = {};
#pragma unroll
    for (int kk = 0; kk < LIB; kk += 32) {
      bf16x8 av = *(const bf16x8*)&Asm[lr * 264 + kk + lq * 8];
      bf16x8 bv = *(const bf16x8*)&Bts[(w * 16 + lr) * 264 + kk + lq * 8];
      acc = __builtin_amdgcn_mfma_f32_16x16x32_bf16(av, bv, acc, 0, 0, 0);
    }
#pragma unroll
    for (int r = 0; r < 4; ++r) {
      const int rowc = lq * 4 + r;
      if (ch + rowc < cnt) {
        const size_t oi = out_off + (size_t)list[ch + rowc] * LIB
                        + (n0 + w * 16 + lr);
        if (of32) ((float*)a.out)[oi] = acc[r];
        else      ((u16*)a.out)[oi] = f2bf(acc[r]);
      }
    }
  }
}

extern "C" void kernel_launch(void* const* d_in, const int* in_sizes, int n_in,
                              void* d_out, int out_size, void* d_ws, size_t ws_size,
                              hipStream_t stream) {
  char* p = (char*)d_ws;
  auto alloc = [&](size_t bytes) { char* r = p; p += (bytes + 255) & ~(size_t)255; return r; };
  u16* all_state = (u16*)alloc((size_t)BATCH * DIN * 2);
  u16* h_x   = (u16*)alloc((size_t)BATCH * HID * 2);
  u16* h_y   = (u16*)alloc((size_t)BATCH * HID * 2);
  u16* cls_y = (u16*)alloc((size_t)BATCH * LIB * 2);
  u16* WT1x  = (u16*)alloc((size_t)HID * DIN * 2);
  u16* WT1y  = (u16*)alloc((size_t)HID * DIN * 2);
  u16* WT2y  = (u16*)alloc((size_t)LIB * HID * 2);
  u16* T     = (u16*)alloc((size_t)LIB * HID * 2);   // (Wx2@nX)^T, bt layout
  float* b2x = (float*)alloc((size_t)LIB * 4);       // nX^T @ bx2, f32

  const void* state = d_in[0];
  const void* opt   = d_in[1];

  // 1) prep: concat + WT1x/WT1y/WT2y + T-gemm + b' (996 blocks, 17.4KB LDS)
  PrepArgs pa;
  pa.state = state; pa.opt = (const int*)opt; pa.emb = d_in[2];
  pa.Wx1 = d_in[3]; pa.Wx2 = d_in[5]; pa.bx2 = d_in[6];
  pa.Wy1 = d_in[7]; pa.Wy2 = d_in[9]; pa.nX = d_in[11];
  pa.all_state = all_state; pa.WT1x = WT1x; pa.WT1y = WT1y; pa.WT2y = WT2y;
  pa.T = T; pa.b2x = b2x;
  prep_k<<<PREP_BLOCKS, 256, 0, stream>>>(pa);

  // 2) layer 1 (relu): 128x64 tiles -> 1024 blocks = 4/CU (barrier overlap)
  GArg g1x{all_state, WT1x, d_in[4], h_x, 0, 0};
  GArg g1y{all_state, WT1y, d_in[8], h_y, 0, 0};
  gemm_bt<128, 64, 2, true><<<dim3(HID / 64, BATCH / 128, 2), 256, 0, stream>>>(
      g1x, g1y, HID, DIN, state, opt);

  // 3) fused layer-2, BK=128 (8 K-iters): z=0 -> out0 = h_x @ T^T + b'
  //                                       z=1 -> cls_y = h_y @ Wy2^T + by2
  GArg g2x{h_x, T, b2x, d_out, 1, 1};
  GArg g2y{h_y, WT2y, d_in[10], cls_y, 0, 0};
  gemm_bt<64, 64, 4, false><<<dim3(LIB / 64, BATCH / 64, 2), 256, 0, stream>>>(
      g2x, g2y, LIB, HID, state, opt);

  // 4) tail: routed gatherY only -> out1 (256 blocks, barrier-free scan)
  TailArgs ta{cls_y, d_in[12], state, (const int*)opt, d_out};
  tail_k<<<256, 256, 0, stream>>>(ta);
}

// Round 12
// 150.069 us; speedup vs baseline: 1.0471x; 1.0153x over previous
//
#include <hip/hip_runtime.h>

typedef unsigned short u16;
typedef unsigned int u32;

using f32x4  = __attribute__((ext_vector_type(4))) float;
using bf16x8 = __attribute__((ext_vector_type(8))) __bf16;

#define DEV __device__ __forceinline__

DEV u16 f2bf(float f) {                       // RTNE f32 -> bf16
  union { float f; u32 u; } x; x.f = f;
  return (u16)((x.u + 0x7fffu + ((x.u >> 16) & 1u)) >> 16);
}
DEV float bf2f(u16 h) {
  union { u32 u; float f; } x; x.u = ((u32)h) << 16;
  return x.f;
}

DEV void async_cp16(const u16* g, u16* l) {   // 16B global -> LDS direct
  __builtin_amdgcn_global_load_lds((const __attribute__((address_space(1))) void*)g,
                                   (__attribute__((address_space(3))) void*)l,
                                   16, 0, 0);
}

static constexpr int BATCH = 4096;
static constexpr int FEAT  = 512;
static constexpr int EMB   = 64;
static constexpr int HID   = 1024;
static constexpr int NC    = 64;
static constexpr int DIN   = 576;   // FEAT + EMB
static constexpr int LIB   = 256;   // LIB_X == LIB_Y == OUT_J

// ---- cheap per-block dtype / index-width detection (1 load/thread) ---------
DEV void detect_lite(const u32* __restrict__ sraw, const u32* __restrict__ oraw,
                     int* isf32, int* ostr) {
  __shared__ int cib, conz;
  const int t = threadIdx.x;
  if (t == 0) { cib = 0; conz = 0; }
  u32 w = sraw[t];
  u32 e = (w >> 7) & 0xFFu;
  unsigned long long m1 = __ballot(e >= 100 && e <= 142);
  unsigned long long m2 = __ballot((t & 1) && oraw[t] != 0);
  __syncthreads();
  if ((t & 63) == 0) {
    atomicAdd(&cib, __popcll(m1));
    atomicAdd(&conz, __popcll(m2));
  }
  __syncthreads();
  *isf32 = (cib < 128) ? 1 : 0;               // low halves not bf16-like -> f32
  *ostr  = (conz == 0) ? 2 : 1;               // all odd words zero -> int64
}

// ---- load 16 elems at element-offset `off`, convert to bf16 ----------------
DEV void load16_bf(u16* v, const void* __restrict__ in, size_t off, int isf32) {
  if (isf32) {
    const float4* s = (const float4*)((const float*)in + off);
    float4 a0 = s[0], a1 = s[1], a2 = s[2], a3 = s[3];
    v[0] = f2bf(a0.x); v[1] = f2bf(a0.y); v[2]  = f2bf(a0.z); v[3]  = f2bf(a0.w);
    v[4] = f2bf(a1.x); v[5] = f2bf(a1.y); v[6]  = f2bf(a1.z); v[7]  = f2bf(a1.w);
    v[8] = f2bf(a2.x); v[9] = f2bf(a2.y); v[10] = f2bf(a2.z); v[11] = f2bf(a2.w);
    v[12] = f2bf(a3.x); v[13] = f2bf(a3.y); v[14] = f2bf(a3.z); v[15] = f2bf(a3.w);
  } else {
    const uint4* s = (const uint4*)((const u16*)in + off);
    *(uint4*)&v[0] = s[0];
    *(uint4*)&v[8] = s[1];
  }
}

// ---- 64x64 transpose tile (bf16-ifying), vectorized both directions --------
DEV void do_transpose64(u16* lds, const void* __restrict__ in,
                        u16* __restrict__ out, int R, int C,
                        int by, int bx, int isf32) {
  u16* tile = lds;                            // 64*72 u16
  const int t = threadIdx.x;
  {
    const int r = t >> 2, c0 = (t & 3) * 16;
    u16 v[16];
    load16_bf(v, in, (size_t)(by * 64 + r) * C + (bx * 64 + c0), isf32);
    *(uint4*)&tile[r * 72 + c0]     = *(uint4*)&v[0];
    *(uint4*)&tile[r * 72 + c0 + 8] = *(uint4*)&v[8];
  }
  __syncthreads();
  {
    const int c = t & 63, rs = (t >> 6) * 16;
    u16 w[16];
#pragma unroll
    for (int i = 0; i < 16; ++i) w[i] = tile[(rs + i) * 72 + c];
    size_t oo = (size_t)(bx * 64 + c) * R + (by * 64 + rs);
    *(uint4*)&out[oo]     = *(uint4*)&w[0];
    *(uint4*)&out[oo + 8] = *(uint4*)&w[8];
  }
}

// ---- T-gemm: T[j][q] = sum_i nX[i][j] * Wx2[q][i]  (bt layout for gemm2-x) -
DEV void tgemm_task(u16* lds, const void* __restrict__ nX,
                    const void* __restrict__ Wx2, u16* __restrict__ T,
                    int mt, int nt, int isf32) {
  u16* Als = lds;                 // [64 j][72]  (64 i-slab + pad)
  u16* Bls = lds + 64 * 72;       // [2*64 q][32]
  const int t = threadIdx.x;
  const int m0 = mt * 64, q0 = nt * 64;
  const int lane = t & 63, wid = t >> 6;
  const int wm = wid >> 1, wn = wid & 1;
  const int lr = lane & 15, lq = lane >> 4;
  f32x4 acc[2][2] = {};
  for (int k0 = 0; k0 < LIB; k0 += 64) {
    __syncthreads();
    {
      const int r = t >> 2, c0 = (t & 3) * 16;
      u16 v[16];
      load16_bf(v, nX, (size_t)(k0 + r) * LIB + m0 + c0, isf32);
#pragma unroll
      for (int j = 0; j < 16; ++j) Als[(c0 + j) * 72 + r] = v[j];
      const int q = t >> 2, ic = (t & 3) * 16;
      u16 w16[16];
      load16_bf(w16, Wx2, (size_t)(q0 + q) * LIB + k0 + ic, isf32);
      u16* dst = &Bls[((ic >> 5) * 64 + q) * 32 + (ic & 31)];
      *(uint4*)dst       = *(uint4*)&w16[0];
      *(uint4*)(dst + 8) = *(uint4*)&w16[8];
    }
    __syncthreads();
#pragma unroll
    for (int sl = 0; sl < 2; ++sl) {
      bf16x8 av[2], bv[2];
#pragma unroll
      for (int i2 = 0; i2 < 2; ++i2)
        av[i2] = *(const bf16x8*)&Als[(wm * 32 + i2 * 16 + lr) * 72 + sl * 32 + lq * 8];
#pragma unroll
      for (int j2 = 0; j2 < 2; ++j2)
        bv[j2] = *(const bf16x8*)&Bls[(sl * 64 + wn * 32 + j2 * 16 + lr) * 32 + lq * 8];
#pragma unroll
      for (int i2 = 0; i2 < 2; ++i2)
#pragma unroll
        for (int j2 = 0; j2 < 2; ++j2)
          acc[i2][j2] = __builtin_amdgcn_mfma_f32_16x16x32_bf16(av[i2], bv[j2], acc[i2][j2], 0, 0, 0);
    }
  }
#pragma unroll
  for (int j2 = 0; j2 < 2; ++j2) {
    const int gc = q0 + wn * 32 + j2 * 16 + lr;
#pragma unroll
    for (int i2 = 0; i2 < 2; ++i2) {
      const int gr = m0 + wm * 32 + i2 * 16 + lq * 4;
#pragma unroll
      for (int r = 0; r < 4; ++r)
        T[(size_t)(gr + r) * HID + gc] = f2bf(acc[i2][j2][r]);
    }
  }
}

// ---- prep: concat | WT1x | WT1y | WT2y | T-gemm | bias' (r8-proven) --------
struct PrepArgs {
  const void *state, *emb, *Wx1, *Wy1, *Wy2, *Wx2, *nX, *bx2;
  const int* opt;
  u16 *all_state, *WT1x, *WT1y, *WT2y, *T;
  float* b2x;
};
static constexpr int PB_CONCAT = BATCH * 36 / 256;            // 576
static constexpr int PB_WT1 = (DIN / 64) * (HID / 64);        // 144
static constexpr int PB_WT2 = (HID / 64) * (LIB / 64);        // 64
static constexpr int PB_TG  = (LIB / 64) * (HID / 64);        // 64
static constexpr int PB_BIAS = 4;
static constexpr int PREP_BLOCKS = PB_CONCAT + 2 * PB_WT1 + PB_WT2 + PB_TG
                                 + PB_BIAS;                   // 996

__global__ __launch_bounds__(256) void prep_k(PrepArgs a) {
  __shared__ __align__(16) u16 plds[64 * 72 + 128 * 32];      // 17408 B
  __shared__ float red[4][64];
  int isf32, os;
  detect_lite((const u32*)a.state, (const u32*)a.opt, &isf32, &os);
  int bid = blockIdx.x;
  const int t = threadIdx.x;
  if (bid < PB_CONCAT) {
    int idx = bid * 256 + t;
    int b = idx / 36, ch = idx % 36;
    const void* base;
    size_t srcoff;
    if (ch < 32) { base = a.state; srcoff = (size_t)b * FEAT + ch * 16; }
    else {
      base = a.emb;
      srcoff = (size_t)a.opt[(size_t)b * os] * EMB + (ch - 32) * 16;
    }
    u16 o[16];
    load16_bf(o, base, srcoff, isf32);
    u16* dst = a.all_state + (size_t)b * DIN + ch * 16;
    *(uint4*)dst       = *(const uint4*)&o[0];
    *(uint4*)(dst + 8) = *(const uint4*)&o[8];
    return;
  }
  bid -= PB_CONCAT;
  if (bid < PB_WT1) { do_transpose64(plds, a.Wx1, a.WT1x, DIN, HID, bid >> 4, bid & 15, isf32); return; }
  bid -= PB_WT1;
  if (bid < PB_WT1) { do_transpose64(plds, a.Wy1, a.WT1y, DIN, HID, bid >> 4, bid & 15, isf32); return; }
  bid -= PB_WT1;
  if (bid < PB_WT2) { do_transpose64(plds, a.Wy2, a.WT2y, HID, LIB, bid >> 2, bid & 3, isf32); return; }
  bid -= PB_WT2;
  if (bid < PB_TG) { tgemm_task(plds, a.nX, a.Wx2, a.T, bid & 3, bid >> 2, isf32); return; }
  bid -= PB_TG;
  // bias': b2x[j] = sum_i bx2[i] * nX[i][j]  (4 blocks x 64 j, i-parallel x4)
  {
    const int j = bid * 64 + (t & 63), g = t >> 6;
    float acc = 0.f;
    for (int ii = 0; ii < 64; ++ii) {
      const int i = g * 64 + ii;
      float s = isf32 ? ((const float*)a.bx2)[i] : bf2f(((const u16*)a.bx2)[i]);
      float v = isf32 ? ((const float*)a.nX)[(size_t)i * LIB + j]
                      : bf2f(((const u16*)a.nX)[(size_t)i * LIB + j]);
      acc += s * v;
    }
    red[g][t & 63] = acc;
    __syncthreads();
    if (g == 0)
      a.b2x[j] = red[0][t & 63] + red[1][t & 63] + red[2][t & 63] + red[3][t & 63];
  }
}

// ---- bt-GEMM tile, BK=32*SLABS multi-slab: C = act(A*Bt^T + bias) ----------
template <int BM, int BN, int SLABS, bool RELU>
DEV void gemm_tile(u16* lds, const u16* __restrict__ A, const u16* __restrict__ Bt,
                   const void* bias, void* C, int N, int K, int m0, int n0,
                   int isf32, bool cf32, bool bf32) {
  constexpr int WM = BM / 2, WN = BN / 2, TM = WM / 16, TN = WN / 16;
  u16* As = lds;                       // [SLABS][BM][32]
  u16* Bs = lds + BM * 32 * SLABS;     // [SLABS][BN][32]
  const int t = threadIdx.x;
  const int lane = t & 63, wid = t >> 6;
  const int wm = wid >> 1, wn = wid & 1;
  const int lr = lane & 15, lq = lane >> 4;
  f32x4 acc[TM][TN] = {};
  for (int k0 = 0; k0 < K; k0 += 32 * SLABS) {
    __syncthreads();
#pragma unroll
    for (int sl = 0; sl < SLABS; ++sl) {
#pragma unroll
      for (int u = 0; u < BM / 64; ++u) {
        int unit = u * 256 + t;
        int r = unit >> 2, c8 = (unit & 3) * 8;
        async_cp16(A + (size_t)(m0 + r) * K + (k0 + sl * 32 + c8),
                   &As[(sl * BM + r) * 32 + c8]);
      }
#pragma unroll
      for (int u = 0; u < BN / 64; ++u) {
        int unit = u * 256 + t;
        int r = unit >> 2, c8 = (unit & 3) * 8;
        async_cp16(Bt + (size_t)(n0 + r) * K + (k0 + sl * 32 + c8),
                   &Bs[(sl * BN + r) * 32 + c8]);
      }
    }
    __syncthreads();
#pragma unroll
    for (int sl = 0; sl < SLABS; ++sl) {
      bf16x8 av[TM], bv[TN];
#pragma unroll
      for (int i = 0; i < TM; ++i)
        av[i] = *(const bf16x8*)&As[(sl * BM + wm * WM + i * 16 + lr) * 32 + lq * 8];
#pragma unroll
      for (int j = 0; j < TN; ++j)
        bv[j] = *(const bf16x8*)&Bs[(sl * BN + wn * WN + j * 16 + lr) * 32 + lq * 8];
#pragma unroll
      for (int i = 0; i < TM; ++i)
#pragma unroll
        for (int j = 0; j < TN; ++j)
          acc[i][j] = __builtin_amdgcn_mfma_f32_16x16x32_bf16(av[i], bv[j], acc[i][j], 0, 0, 0);
    }
  }
  // epilogue: C/D layout col=lane&15, row=(lane>>4)*4+r  [m89/m91 verified]
#pragma unroll
  for (int j = 0; j < TN; ++j) {
    const int gc = n0 + wn * WN + j * 16 + lr;
    const float bval = bias
        ? (bf32 ? ((const float*)bias)[gc] : bf2f(((const u16*)bias)[gc]))
        : 0.f;
#pragma unroll
    for (int i = 0; i < TM; ++i) {
      const int gr = m0 + wm * WM + i * 16 + lq * 4;
#pragma unroll
      for (int r = 0; r < 4; ++r) {
        float v = acc[i][j][r] + bval;
        if (RELU) v = fmaxf(v, 0.f);
        const size_t idx = (size_t)(gr + r) * N + gc;
        if (cf32) ((float*)C)[idx] = v;
        else      ((u16*)C)[idx] = f2bf(v);
      }
    }
  }
}

struct GArg { const u16* A; const u16* Bt; const void* bias; void* C; int cflag; int bflag; };

// r6-proven orientation: x = n-tile, y = m-tile, z = head
template <int BM, int BN, int SLABS, bool RELU>
__global__ __launch_bounds__(256) void gemm_bt(GArg g0, GArg g1, int N, int K,
                                               const void* state, const void* opt) {
  __shared__ __align__(16) u16 lds[(BM + BN) * 32 * SLABS];
  int isf32, os;
  detect_lite((const u32*)state, (const u32*)opt, &isf32, &os);
  const GArg g = blockIdx.z ? g1 : g0;
  gemm_tile<BM, BN, SLABS, RELU>(lds, g.A, g.Bt, g.bias, g.C, N, K,
                                 blockIdx.y * BM, blockIdx.x * BN,
                                 isf32, g.cflag && isf32, g.bflag || isf32);
}

// ---- tail: routed gatherY (512 blocks: class x 4 col-tiles x 2 b-halves) ---
// Each half scans a DISJOINT b-range [h*2048,(h+1)*2048): row sets disjoint by
// construction, so the barrier-free (order-nondeterministic) list build is
// safe -- each block processes ALL chunks of its own list.
struct TailArgs {
  const u16* cls_y;
  const void *nY, *state;
  const int* opt;
  void* out;            // out1 at BATCH*LIB
};

__global__ __launch_bounds__(256) void tail_k(TailArgs a) {
  __shared__ __align__(16) u16 lds[25216];  // Bts 64x264 | Asm 16x264 | list
  __shared__ int lcnt;
  int isf32, os;
  detect_lite((const u32*)a.state, (const u32*)a.opt, &isf32, &os);
  const bool of32 = (isf32 != 0);
  const int t = threadIdx.x;
  const int lane = t & 63, w = t >> 6, lr = lane & 15, lq = lane >> 4;

  u16* Bts  = lds;            // [64 n][264]  B[n][k] = nY[m][k][n0+n]
  u16* Asm  = lds + 16896;    // [16][264]
  u16* list = lds + 21120;    // up to 2048 row ids (half-batch)
  const int m = blockIdx.x >> 3;
  const int n0 = ((blockIdx.x >> 1) & 3) * 64;
  const int half = blockIdx.x & 1;    // scan b in [half*2048, half*2048+2048)
  if (t == 0) lcnt = 0;

#pragma unroll
  for (int pass = 0; pass < 4; ++pass) {
    const int k = pass * 64 + (t >> 2), nc = (t & 3) * 16;
    u16 v[16];
    load16_bf(v, a.nY, ((size_t)m * LIB + k) * LIB + n0 + nc, isf32);
#pragma unroll
    for (int j = 0; j < 16; ++j) Bts[(nc + j) * 264 + k] = v[j];
  }

  // build row list for class m within this block's b-half: per-wave chunk
  // reservation, no barriers in the scan loop (intra-list order irrelevant)
  __syncthreads();            // lcnt=0 visible
  const int bstart = half * (BATCH / 2), bend = bstart + BATCH / 2;
  for (int base = bstart; base < bend; base += 256) {
    const int b = base + t;
    const int e = a.opt[(size_t)b * os];
    unsigned long long mk = __ballot(e == m);
    const int nw = __popcll(mk);
    int wbase = 0;
    if (lane == 0 && nw) wbase = atomicAdd(&lcnt, nw);
    wbase = __shfl(wbase, 0);
    const int mypre = __popcll(mk & ((1ull << lane) - 1ull));
    if (e == m) list[wbase + mypre] = (u16)b;
  }
  __syncthreads();
  const int cnt = lcnt;
  const size_t out_off = (size_t)BATCH * LIB;

  for (int ch = 0; ch < cnt; ch += 16) {
    __syncthreads();
    {
      const int r = t >> 4, cb = (t & 15) * 16;
      if (ch + r < cnt) {
        const u16* src = a.cls_y + (size_t)list[ch + r] * LIB + cb;
        *(uint4*)&Asm[r * 264 + cb]     = *(const uint4*)src;
        *(uint4*)&Asm[r * 264 + cb + 8] = *(const uint4*)(src + 8);
      } else {
        uint4 z{0, 0, 0, 0};
        *(uint4*)&Asm[r * 264 + cb]     = z;
        *(uint4*)&Asm[r * 264 + cb + 8] = z;
      }
    }
    __syncthreads();
    f32x4 acc = {};
#pragma unroll
    for (int kk = 0; kk < LIB; kk += 32) {
      bf16x8 av = *(const bf16x8*)&Asm[lr * 264 + kk + lq * 8];
      bf16x8 bv = *(const bf16x8*)&Bts[(w * 16 + lr) * 264 + kk + lq * 8];
      acc = __builtin_amdgcn_mfma_f32_16x16x32_bf16(av, bv, acc, 0, 0, 0);
    }
#pragma unroll
    for (int r = 0; r < 4; ++r) {
      const int rowc = lq * 4 + r;
      if (ch + rowc < cnt) {
        const size_t oi = out_off + (size_t)list[ch + rowc] * LIB
                        + (n0 + w * 16 + lr);
        if (of32) ((float*)a.out)[oi] = acc[r];
        else      ((u16*)a.out)[oi] = f2bf(acc[r]);
      }
    }
  }
}

extern "C" void kernel_launch(void* const* d_in, const int* in_sizes, int n_in,
                              void* d_out, int out_size, void* d_ws, size_t ws_size,
                              hipStream_t stream) {
  char* p = (char*)d_ws;
  auto alloc = [&](size_t bytes) { char* r = p; p += (bytes + 255) & ~(size_t)255; return r; };
  u16* all_state = (u16*)alloc((size_t)BATCH * DIN * 2);
  u16* h_x   = (u16*)alloc((size_t)BATCH * HID * 2);
  u16* h_y   = (u16*)alloc((size_t)BATCH * HID * 2);
  u16* cls_y = (u16*)alloc((size_t)BATCH * LIB * 2);
  u16* WT1x  = (u16*)alloc((size_t)HID * DIN * 2);
  u16* WT1y  = (u16*)alloc((size_t)HID * DIN * 2);
  u16* WT2y  = (u16*)alloc((size_t)LIB * HID * 2);
  u16* T     = (u16*)alloc((size_t)LIB * HID * 2);   // (Wx2@nX)^T, bt layout
  float* b2x = (float*)alloc((size_t)LIB * 4);       // nX^T @ bx2, f32

  const void* state = d_in[0];
  const void* opt   = d_in[1];

  // 1) prep: concat + WT1x/WT1y/WT2y + T-gemm + b' (996 blocks, 17.4KB LDS)
  PrepArgs pa;
  pa.state = state; pa.opt = (const int*)opt; pa.emb = d_in[2];
  pa.Wx1 = d_in[3]; pa.Wx2 = d_in[5]; pa.bx2 = d_in[6];
  pa.Wy1 = d_in[7]; pa.Wy2 = d_in[9]; pa.nX = d_in[11];
  pa.all_state = all_state; pa.WT1x = WT1x; pa.WT1y = WT1y; pa.WT2y = WT2y;
  pa.T = T; pa.b2x = b2x;
  prep_k<<<PREP_BLOCKS, 256, 0, stream>>>(pa);

  // 2) layer 1 (relu): 128x64 tiles, BK=96 (6 K-iters; 36.9KB LDS, 4/CU)
  GArg g1x{all_state, WT1x, d_in[4], h_x, 0, 0};
  GArg g1y{all_state, WT1y, d_in[8], h_y, 0, 0};
  gemm_bt<128, 64, 3, true><<<dim3(HID / 64, BATCH / 128, 2), 256, 0, stream>>>(
      g1x, g1y, HID, DIN, state, opt);

  // 3) fused layer-2, BK=128 (8 K-iters): z=0 -> out0 = h_x @ T^T + b'
  //                                       z=1 -> cls_y = h_y @ Wy2^T + by2
  GArg g2x{h_x, T, b2x, d_out, 1, 1};
  GArg g2y{h_y, WT2y, d_in[10], cls_y, 0, 0};
  gemm_bt<64, 64, 4, false><<<dim3(LIB / 64, BATCH / 64, 2), 256, 0, stream>>>(
      g2x, g2y, LIB, HID, state, opt);

  // 4) tail: routed gatherY -> out1 (512 blocks = 2/CU, disjoint b-halves)
  TailArgs ta{cls_y, d_in[12], state, (const int*)opt, d_out};
  tail_k<<<512, 256, 0, stream>>>(ta);
}

// Round 13
// 148.411 us; speedup vs baseline: 1.0588x; 1.0112x over previous
//
#include <hip/hip_runtime.h>

typedef unsigned short u16;
typedef unsigned int u32;

using f32x4  = __attribute__((ext_vector_type(4))) float;
using bf16x8 = __attribute__((ext_vector_type(8))) __bf16;

#define DEV __device__ __forceinline__

DEV u16 f2bf(float f) {                       // RTNE f32 -> bf16
  union { float f; u32 u; } x; x.f = f;
  return (u16)((x.u + 0x7fffu + ((x.u >> 16) & 1u)) >> 16);
}
DEV float bf2f(u16 h) {
  union { u32 u; float f; } x; x.u = ((u32)h) << 16;
  return x.f;
}

DEV void async_cp16(const u16* g, u16* l) {   // 16B global -> LDS direct
  __builtin_amdgcn_global_load_lds((const __attribute__((address_space(1))) void*)g,
                                   (__attribute__((address_space(3))) void*)l,
                                   16, 0, 0);
}

static constexpr int BATCH = 4096;
static constexpr int FEAT  = 512;
static constexpr int EMB   = 64;
static constexpr int HID   = 1024;
static constexpr int NC    = 64;
static constexpr int DIN   = 576;   // FEAT + EMB
static constexpr int LIB   = 256;   // LIB_X == LIB_Y == OUT_J

// ---- cheap per-block dtype / index-width detection (1 load/thread) ---------
DEV void detect_lite(const u32* __restrict__ sraw, const u32* __restrict__ oraw,
                     int* isf32, int* ostr) {
  __shared__ int cib, conz;
  const int t = threadIdx.x;
  if (t == 0) { cib = 0; conz = 0; }
  u32 w = sraw[t];
  u32 e = (w >> 7) & 0xFFu;
  unsigned long long m1 = __ballot(e >= 100 && e <= 142);
  unsigned long long m2 = __ballot((t & 1) && oraw[t] != 0);
  __syncthreads();
  if ((t & 63) == 0) {
    atomicAdd(&cib, __popcll(m1));
    atomicAdd(&conz, __popcll(m2));
  }
  __syncthreads();
  *isf32 = (cib < 128) ? 1 : 0;               // low halves not bf16-like -> f32
  *ostr  = (conz == 0) ? 2 : 1;               // all odd words zero -> int64
}

// ---- load 16 elems at element-offset `off`, convert to bf16 ----------------
DEV void load16_bf(u16* v, const void* __restrict__ in, size_t off, int isf32) {
  if (isf32) {
    const float4* s = (const float4*)((const float*)in + off);
    float4 a0 = s[0], a1 = s[1], a2 = s[2], a3 = s[3];
    v[0] = f2bf(a0.x); v[1] = f2bf(a0.y); v[2]  = f2bf(a0.z); v[3]  = f2bf(a0.w);
    v[4] = f2bf(a1.x); v[5] = f2bf(a1.y); v[6]  = f2bf(a1.z); v[7]  = f2bf(a1.w);
    v[8] = f2bf(a2.x); v[9] = f2bf(a2.y); v[10] = f2bf(a2.z); v[11] = f2bf(a2.w);
    v[12] = f2bf(a3.x); v[13] = f2bf(a3.y); v[14] = f2bf(a3.z); v[15] = f2bf(a3.w);
  } else {
    const uint4* s = (const uint4*)((const u16*)in + off);
    *(uint4*)&v[0] = s[0];
    *(uint4*)&v[8] = s[1];
  }
}

// ---- 64x64 transpose tile (bf16-ifying), vectorized both directions --------
DEV void do_transpose64(u16* lds, const void* __restrict__ in,
                        u16* __restrict__ out, int R, int C,
                        int by, int bx, int isf32) {
  u16* tile = lds;                            // 64*72 u16
  const int t = threadIdx.x;
  {
    const int r = t >> 2, c0 = (t & 3) * 16;
    u16 v[16];
    load16_bf(v, in, (size_t)(by * 64 + r) * C + (bx * 64 + c0), isf32);
    *(uint4*)&tile[r * 72 + c0]     = *(uint4*)&v[0];
    *(uint4*)&tile[r * 72 + c0 + 8] = *(uint4*)&v[8];
  }
  __syncthreads();
  {
    const int c = t & 63, rs = (t >> 6) * 16;
    u16 w[16];
#pragma unroll
    for (int i = 0; i < 16; ++i) w[i] = tile[(rs + i) * 72 + c];
    size_t oo = (size_t)(bx * 64 + c) * R + (by * 64 + rs);
    *(uint4*)&out[oo]     = *(uint4*)&w[0];
    *(uint4*)&out[oo + 8] = *(uint4*)&w[8];
  }
}

// ---- T-gemm: T[j][q] = sum_i nX[i][j] * Wx2[q][i]  (bt layout for gemm2-x) -
DEV void tgemm_task(u16* lds, const void* __restrict__ nX,
                    const void* __restrict__ Wx2, u16* __restrict__ T,
                    int mt, int nt, int isf32) {
  u16* Als = lds;                 // [64 j][72]  (64 i-slab + pad)
  u16* Bls = lds + 64 * 72;       // [2*64 q][32]
  const int t = threadIdx.x;
  const int m0 = mt * 64, q0 = nt * 64;
  const int lane = t & 63, wid = t >> 6;
  const int wm = wid >> 1, wn = wid & 1;
  const int lr = lane & 15, lq = lane >> 4;
  f32x4 acc[2][2] = {};
  for (int k0 = 0; k0 < LIB; k0 += 64) {
    __syncthreads();
    {
      const int r = t >> 2, c0 = (t & 3) * 16;
      u16 v[16];
      load16_bf(v, nX, (size_t)(k0 + r) * LIB + m0 + c0, isf32);
#pragma unroll
      for (int j = 0; j < 16; ++j) Als[(c0 + j) * 72 + r] = v[j];
      const int q = t >> 2, ic = (t & 3) * 16;
      u16 w16[16];
      load16_bf(w16, Wx2, (size_t)(q0 + q) * LIB + k0 + ic, isf32);
      u16* dst = &Bls[((ic >> 5) * 64 + q) * 32 + (ic & 31)];
      *(uint4*)dst       = *(uint4*)&w16[0];
      *(uint4*)(dst + 8) = *(uint4*)&w16[8];
    }
    __syncthreads();
#pragma unroll
    for (int sl = 0; sl < 2; ++sl) {
      bf16x8 av[2], bv[2];
#pragma unroll
      for (int i2 = 0; i2 < 2; ++i2)
        av[i2] = *(const bf16x8*)&Als[(wm * 32 + i2 * 16 + lr) * 72 + sl * 32 + lq * 8];
#pragma unroll
      for (int j2 = 0; j2 < 2; ++j2)
        bv[j2] = *(const bf16x8*)&Bls[(sl * 64 + wn * 32 + j2 * 16 + lr) * 32 + lq * 8];
#pragma unroll
      for (int i2 = 0; i2 < 2; ++i2)
#pragma unroll
        for (int j2 = 0; j2 < 2; ++j2)
          acc[i2][j2] = __builtin_amdgcn_mfma_f32_16x16x32_bf16(av[i2], bv[j2], acc[i2][j2], 0, 0, 0);
    }
  }
#pragma unroll
  for (int j2 = 0; j2 < 2; ++j2) {
    const int gc = q0 + wn * 32 + j2 * 16 + lr;
#pragma unroll
    for (int i2 = 0; i2 < 2; ++i2) {
      const int gr = m0 + wm * 32 + i2 * 16 + lq * 4;
#pragma unroll
      for (int r = 0; r < 4; ++r)
        T[(size_t)(gr + r) * HID + gc] = f2bf(acc[i2][j2][r]);
    }
  }
}

// ---- prep: concat | WT1x | WT1y  (pure copies feeding gemm1; 864 blocks) ---
struct PrepArgs {
  const void *state, *emb, *Wx1, *Wy1;
  const int* opt;
  u16 *all_state, *WT1x, *WT1y;
};
static constexpr int PB_CONCAT = BATCH * 36 / 256;            // 576
static constexpr int PB_WT1 = (DIN / 64) * (HID / 64);        // 144
static constexpr int PREP_BLOCKS = PB_CONCAT + 2 * PB_WT1;    // 864

__global__ __launch_bounds__(256) void prep_k(PrepArgs a) {
  __shared__ __align__(16) u16 plds[64 * 72];                 // 9216 B
  int isf32, os;
  detect_lite((const u32*)a.state, (const u32*)a.opt, &isf32, &os);
  int bid = blockIdx.x;
  const int t = threadIdx.x;
  if (bid < PB_CONCAT) {
    int idx = bid * 256 + t;
    int b = idx / 36, ch = idx % 36;
    const void* base;
    size_t srcoff;
    if (ch < 32) { base = a.state; srcoff = (size_t)b * FEAT + ch * 16; }
    else {
      base = a.emb;
      srcoff = (size_t)a.opt[(size_t)b * os] * EMB + (ch - 32) * 16;
    }
    u16 o[16];
    load16_bf(o, base, srcoff, isf32);
    u16* dst = a.all_state + (size_t)b * DIN + ch * 16;
    *(uint4*)dst       = *(const uint4*)&o[0];
    *(uint4*)(dst + 8) = *(const uint4*)&o[8];
    return;
  }
  bid -= PB_CONCAT;
  if (bid < PB_WT1) { do_transpose64(plds, a.Wx1, a.WT1x, DIN, HID, bid >> 4, bid & 15, isf32); return; }
  bid -= PB_WT1;
  do_transpose64(plds, a.Wy1, a.WT1y, DIN, HID, bid >> 4, bid & 15, isf32);
}

// ---- bt-GEMM tile, BK=32*SLABS multi-slab: C = act(A*Bt^T + bias) ----------
template <int BM, int BN, int SLABS, bool RELU>
DEV void gemm_tile(u16* lds, const u16* __restrict__ A, const u16* __restrict__ Bt,
                   const void* bias, void* C, int N, int K, int m0, int n0,
                   int isf32, bool cf32, bool bf32) {
  constexpr int WM = BM / 2, WN = BN / 2, TM = WM / 16, TN = WN / 16;
  u16* As = lds;                       // [SLABS][BM][32]
  u16* Bs = lds + BM * 32 * SLABS;     // [SLABS][BN][32]
  const int t = threadIdx.x;
  const int lane = t & 63, wid = t >> 6;
  const int wm = wid >> 1, wn = wid & 1;
  const int lr = lane & 15, lq = lane >> 4;
  f32x4 acc[TM][TN] = {};
  for (int k0 = 0; k0 < K; k0 += 32 * SLABS) {
    __syncthreads();
#pragma unroll
    for (int sl = 0; sl < SLABS; ++sl) {
#pragma unroll
      for (int u = 0; u < BM / 64; ++u) {
        int unit = u * 256 + t;
        int r = unit >> 2, c8 = (unit & 3) * 8;
        async_cp16(A + (size_t)(m0 + r) * K + (k0 + sl * 32 + c8),
                   &As[(sl * BM + r) * 32 + c8]);
      }
#pragma unroll
      for (int u = 0; u < BN / 64; ++u) {
        int unit = u * 256 + t;
        int r = unit >> 2, c8 = (unit & 3) * 8;
        async_cp16(Bt + (size_t)(n0 + r) * K + (k0 + sl * 32 + c8),
                   &Bs[(sl * BN + r) * 32 + c8]);
      }
    }
    __syncthreads();
#pragma unroll
    for (int sl = 0; sl < SLABS; ++sl) {
      bf16x8 av[TM], bv[TN];
#pragma unroll
      for (int i = 0; i < TM; ++i)
        av[i] = *(const bf16x8*)&As[(sl * BM + wm * WM + i * 16 + lr) * 32 + lq * 8];
#pragma unroll
      for (int j = 0; j < TN; ++j)
        bv[j] = *(const bf16x8*)&Bs[(sl * BN + wn * WN + j * 16 + lr) * 32 + lq * 8];
#pragma unroll
      for (int i = 0; i < TM; ++i)
#pragma unroll
        for (int j = 0; j < TN; ++j)
          acc[i][j] = __builtin_amdgcn_mfma_f32_16x16x32_bf16(av[i], bv[j], acc[i][j], 0, 0, 0);
    }
  }
  // epilogue: C/D layout col=lane&15, row=(lane>>4)*4+r  [m89/m91 verified]
#pragma unroll
  for (int j = 0; j < TN; ++j) {
    const int gc = n0 + wn * WN + j * 16 + lr;
    const float bval = bias
        ? (bf32 ? ((const float*)bias)[gc] : bf2f(((const u16*)bias)[gc]))
        : 0.f;
#pragma unroll
    for (int i = 0; i < TM; ++i) {
      const int gr = m0 + wm * WM + i * 16 + lq * 4;
#pragma unroll
      for (int r = 0; r < 4; ++r) {
        float v = acc[i][j][r] + bval;
        if (RELU) v = fmaxf(v, 0.f);
        const size_t idx = (size_t)(gr + r) * N + gc;
        if (cf32) ((float*)C)[idx] = v;
        else      ((u16*)C)[idx] = f2bf(v);
      }
    }
  }
}

// ---- gemm1: layer-1 both heads (1024 blocks, r12 mapping preserved via 1D
// x-fastest decode) + appended side-tasks feeding gemm2/gemm3:
// 1024..1087 WT2y transpose | 1088..1151 T-gemm | 1152..1155 bias'
struct G1Args {
  const u16 *all_state, *WT1x, *WT1y;
  const void *bx1, *by1, *Wy2, *nX, *Wx2, *bx2, *state, *opt;
  u16 *h_x, *h_y, *WT2y, *T;
  float* b2x;
};
static constexpr int G1_GEMM = 1024;
static constexpr int G1_BLOCKS = G1_GEMM + 64 + 64 + 4;       // 1156

__global__ __launch_bounds__(256) void gemm1_k(G1Args a) {
  __shared__ __align__(16) u16 lds[(128 + 64) * 96];          // 36864 B
  __shared__ float red[4][64];
  int isf32, os;
  detect_lite((const u32*)a.state, (const u32*)a.opt, &isf32, &os);
  int bid = blockIdx.x;
  const int t = threadIdx.x;
  if (bid < G1_GEMM) {
    // identical to r12's dim3(16,32,2) x-fastest linearization
    const int x = bid & 15, y = (bid >> 4) & 31, z = bid >> 9;
    gemm_tile<128, 64, 3, true>(lds,
        a.all_state, z ? a.WT1y : a.WT1x, z ? a.by1 : a.bx1,
        z ? a.h_y : a.h_x, HID, DIN, y * 128, x * 64, isf32, false, isf32);
    return;
  }
  bid -= G1_GEMM;
  if (bid < 64) { do_transpose64(lds, a.Wy2, a.WT2y, HID, LIB, bid >> 2, bid & 3, isf32); return; }
  bid -= 64;
  if (bid < 64) { tgemm_task(lds, a.nX, a.Wx2, a.T, bid & 3, bid >> 2, isf32); return; }
  bid -= 64;
  // bias': b2x[j] = sum_i bx2[i] * nX[i][j]  (4 blocks x 64 j, i-parallel x4)
  {
    const int j = bid * 64 + (t & 63), g = t >> 6;
    float acc = 0.f;
    for (int ii = 0; ii < 64; ++ii) {
      const int i = g * 64 + ii;
      float s = isf32 ? ((const float*)a.bx2)[i] : bf2f(((const u16*)a.bx2)[i]);
      float v = isf32 ? ((const float*)a.nX)[(size_t)i * LIB + j]
                      : bf2f(((const u16*)a.nX)[(size_t)i * LIB + j]);
      acc += s * v;
    }
    red[g][t & 63] = acc;
    __syncthreads();
    if (g == 0)
      a.b2x[j] = red[0][t & 63] + red[1][t & 63] + red[2][t & 63] + red[3][t & 63];
  }
}

struct GArg { const u16* A; const u16* Bt; const void* bias; void* C; int cflag; int bflag; };

// r6-proven orientation: x = n-tile, y = m-tile, z = head
template <int BM, int BN, int SLABS, bool RELU>
__global__ __launch_bounds__(256) void gemm_bt(GArg g0, GArg g1, int N, int K,
                                               const void* state, const void* opt) {
  __shared__ __align__(16) u16 lds[(BM + BN) * 32 * SLABS];
  int isf32, os;
  detect_lite((const u32*)state, (const u32*)opt, &isf32, &os);
  const GArg g = blockIdx.z ? g1 : g0;
  gemm_tile<BM, BN, SLABS, RELU>(lds, g.A, g.Bt, g.bias, g.C, N, K,
                                 blockIdx.y * BM, blockIdx.x * BN,
                                 isf32, g.cflag && isf32, g.bflag || isf32);
}

// ---- tail: routed gatherY (512 blocks: class x 4 col-tiles x 2 b-halves) ---
// Each half scans a DISJOINT b-range: row sets disjoint by construction, so
// the barrier-free (order-nondeterministic) list build is safe.
struct TailArgs {
  const u16* cls_y;
  const void *nY, *state;
  const int* opt;
  void* out;            // out1 at BATCH*LIB
};

__global__ __launch_bounds__(256) void tail_k(TailArgs a) {
  __shared__ __align__(16) u16 lds[25216];  // Bts 64x264 | Asm 16x264 | list
  __shared__ int lcnt;
  int isf32, os;
  detect_lite((const u32*)a.state, (const u32*)a.opt, &isf32, &os);
  const bool of32 = (isf32 != 0);
  const int t = threadIdx.x;
  const int lane = t & 63, w = t >> 6, lr = lane & 15, lq = lane >> 4;

  u16* Bts  = lds;            // [64 n][264]  B[n][k] = nY[m][k][n0+n]
  u16* Asm  = lds + 16896;    // [16][264]
  u16* list = lds + 21120;    // up to 2048 row ids (half-batch)
  const int m = blockIdx.x >> 3;
  const int n0 = ((blockIdx.x >> 1) & 3) * 64;
  const int half = blockIdx.x & 1;    // scan b in [half*2048, half*2048+2048)
  if (t == 0) lcnt = 0;

#pragma unroll
  for (int pass = 0; pass < 4; ++pass) {
    const int k = pass * 64 + (t >> 2), nc = (t & 3) * 16;
    u16 v[16];
    load16_bf(v, a.nY, ((size_t)m * LIB + k) * LIB + n0 + nc, isf32);
#pragma unroll
    for (int j = 0; j < 16; ++j) Bts[(nc + j) * 264 + k] = v[j];
  }

  // build row list for class m within this block's b-half: per-wave chunk
  // reservation, no barriers in the scan loop (intra-list order irrelevant)
  __syncthreads();            // lcnt=0 visible
  const int bstart = half * (BATCH / 2), bend = bstart + BATCH / 2;
  for (int base = bstart; base < bend; base += 256) {
    const int b = base + t;
    const int e = a.opt[(size_t)b * os];
    unsigned long long mk = __ballot(e == m);
    const int nw = __popcll(mk);
    int wbase = 0;
    if (lane == 0 && nw) wbase = atomicAdd(&lcnt, nw);
    wbase = __shfl(wbase, 0);
    const int mypre = __popcll(mk & ((1ull << lane) - 1ull));
    if (e == m) list[wbase + mypre] = (u16)b;
  }
  __syncthreads();
  const int cnt = lcnt;
  const size_t out_off = (size_t)BATCH * LIB;

  for (int ch = 0; ch < cnt; ch += 16) {
    __syncthreads();
    {
      const int r = t >> 4, cb = (t & 15) * 16;
      if (ch + r < cnt) {
        const u16* src = a.cls_y + (size_t)list[ch + r] * LIB + cb;
        *(uint4*)&Asm[r * 264 + cb]     = *(const uint4*)src;
        *(uint4*)&Asm[r * 264 + cb + 8] = *(const uint4*)(src + 8);
      } else {
        uint4 z{0, 0, 0, 0};
        *(uint4*)&Asm[r * 264 + cb]     = z;
        *(uint4*)&Asm[r * 264 + cb + 8] = z;
      }
    }
    __syncthreads();
    f32x4 acc = {};
#pragma unroll
    for (int kk = 0; kk < LIB; kk += 32) {
      bf16x8 av = *(const bf16x8*)&Asm[lr * 264 + kk + lq * 8];
      bf16x8 bv = *(const bf16x8*)&Bts[(w * 16 + lr) * 264 + kk + lq * 8];
      acc = __builtin_amdgcn_mfma_f32_16x16x32_bf16(av, bv, acc, 0, 0, 0);
    }
#pragma unroll
    for (int r = 0; r < 4; ++r) {
      const int rowc = lq * 4 + r;
      if (ch + rowc < cnt) {
        const size_t oi = out_off + (size_t)list[ch + rowc] * LIB
                        + (n0 + w * 16 + lr);
        if (of32) ((float*)a.out)[oi] = acc[r];
        else      ((u16*)a.out)[oi] = f2bf(acc[r]);
      }
    }
  }
}

extern "C" void kernel_launch(void* const* d_in, const int* in_sizes, int n_in,
                              void* d_out, int out_size, void* d_ws, size_t ws_size,
                              hipStream_t stream) {
  char* p = (char*)d_ws;
  auto alloc = [&](size_t bytes) { char* r = p; p += (bytes + 255) & ~(size_t)255; return r; };
  u16* all_state = (u16*)alloc((size_t)BATCH * DIN * 2);
  u16* h_x   = (u16*)alloc((size_t)BATCH * HID * 2);
  u16* h_y   = (u16*)alloc((size_t)BATCH * HID * 2);
  u16* cls_y = (u16*)alloc((size_t)BATCH * LIB * 2);
  u16* WT1x  = (u16*)alloc((size_t)HID * DIN * 2);
  u16* WT1y  = (u16*)alloc((size_t)HID * DIN * 2);
  u16* WT2y  = (u16*)alloc((size_t)LIB * HID * 2);
  u16* T     = (u16*)alloc((size_t)LIB * HID * 2);   // (Wx2@nX)^T, bt layout
  float* b2x = (float*)alloc((size_t)LIB * 4);       // nX^T @ bx2, f32

  const void* state = d_in[0];
  const void* opt   = d_in[1];

  // 1) prep: concat + WT1x/WT1y only (864 pure-copy blocks, 9.2 KB LDS)
  PrepArgs pa;
  pa.state = state; pa.opt = (const int*)opt; pa.emb = d_in[2];
  pa.Wx1 = d_in[3]; pa.Wy1 = d_in[7];
  pa.all_state = all_state; pa.WT1x = WT1x; pa.WT1y = WT1y;
  prep_k<<<PREP_BLOCKS, 256, 0, stream>>>(pa);

  // 2) layer 1 (relu): 128x64, BK=96, 4/CU + WT2y/T/b' backfill (1156 blocks)
  G1Args g1;
  g1.all_state = all_state; g1.WT1x = WT1x; g1.WT1y = WT1y;
  g1.bx1 = d_in[4]; g1.by1 = d_in[8];
  g1.Wy2 = d_in[9]; g1.nX = d_in[11]; g1.Wx2 = d_in[5]; g1.bx2 = d_in[6];
  g1.state = state; g1.opt = opt;
  g1.h_x = h_x; g1.h_y = h_y; g1.WT2y = WT2y; g1.T = T; g1.b2x = b2x;
  gemm1_k<<<G1_BLOCKS, 256, 0, stream>>>(g1);

  // 3) fused layer-2, BK=128 (8 K-iters): z=0 -> out0 = h_x @ T^T + b'
  //                                       z=1 -> cls_y = h_y @ Wy2^T + by2
  GArg g2x{h_x, T, b2x, d_out, 1, 1};
  GArg g2y{h_y, WT2y, d_in[10], cls_y, 0, 0};
  gemm_bt<64, 64, 4, false><<<dim3(LIB / 64, BATCH / 64, 2), 256, 0, stream>>>(
      g2x, g2y, LIB, HID, state, opt);

  // 4) tail: routed gatherY -> out1 (512 blocks = 2/CU, disjoint b-halves)
  TailArgs ta{cls_y, d_in[12], state, (const int*)opt, d_out};
  tail_k<<<512, 256, 0, stream>>>(ta);
}